// Round 3
// baseline (132.145 us; speedup 1.0000x reference)
//
#include <hip/hip_runtime.h>
#include <math.h>

#define D_BINS 59
#define CO     64
#define CI     256
#define NB     4
#define NC     6
#define H_IMG  16
#define W_IMG  44
#define HW     704            // H_IMG * W_IMG
#define NPIX   (NB*NC*HW)     // 16896
#define XD     128
#define YD     128
#define ZD     7
#define NOUT   123            // D_BINS + CO
#define PXB    66             // pixels per k_head block: 256 * 66 == NPIX exactly

// ---------------------------------------------------------------------------
// Double-precision rigid-transform inverse (matches np.linalg.inv to ~1e-15,
// avoiding depth-bin boundary flips downstream).
// ---------------------------------------------------------------------------
__device__ void inv_rigid(const float* __restrict__ M, float* __restrict__ o) {
    double a = M[0], b = M[1], c = M[2], t0 = M[3];
    double d = M[4], e = M[5], f = M[6], t1 = M[7];
    double g = M[8], h = M[9], ii = M[10], t2 = M[11];
    double A00 = e*ii - f*h, A01 = c*h - b*ii, A02 = b*f - c*e;
    double A10 = f*g - d*ii, A11 = a*ii - c*g, A12 = c*d - a*f;
    double A20 = d*h - e*g,  A21 = b*g - a*h,  A22 = a*e - b*d;
    double det = a*A00 + b*A10 + c*A20;
    double inv = 1.0 / det;
    double r00 = A00*inv, r01 = A01*inv, r02 = A02*inv;
    double r10 = A10*inv, r11 = A11*inv, r12 = A12*inv;
    double r20 = A20*inv, r21 = A21*inv, r22 = A22*inv;
    o[0] = (float)r00; o[1] = (float)r01; o[2]  = (float)r02;
    o[3] = (float)(-(r00*t0 + r01*t1 + r02*t2));
    o[4] = (float)r10; o[5] = (float)r11; o[6]  = (float)r12;
    o[7] = (float)(-(r10*t0 + r11*t1 + r12*t2));
    o[8] = (float)r20; o[9] = (float)r21; o[10] = (float)r22;
    o[11] = (float)(-(r20*t0 + r21*t1 + r22*t2));
}

// ---------------------------------------------------------------------------
// Kernel 1: prep. Transpose W (123x256) -> wt (256 x 128, zero-padded) for
// k_head's scalar-cache W path; block 0 also inverts the 24 cam2ego mats.
// ---------------------------------------------------------------------------
__global__ __launch_bounds__(256) void k_pre(
    const float* __restrict__ wd, const float* __restrict__ c2e,
    float* __restrict__ wt, float* __restrict__ e2c) {
    const int o = blockIdx.x;   // 0..127
    const int k = threadIdx.x;  // 0..255
    float v = (o < NOUT) ? wd[(size_t)o * CI + k] : 0.f;
    wt[(size_t)k * 128 + o] = v;
    if (blockIdx.x == 0 && k < NB * NC)
        inv_rigid(c2e + k * 16, e2c + k * 12);
}

// ---------------------------------------------------------------------------
// Kernel 2: depth/feat head. EXACTLY 256 blocks (66 px each) -> perfectly
// balanced across 256 CUs (264 64-px blocks had a 2x makespan tail).
// Waves 0..7: lane = px (0..63), wave-uniform o-strip of 16 -> W rows stream
//   through the scalar cache (s_load), A from LDS conflict-free b32.
// Waves 8..9: the 2 leftover px columns; lane = o, A via LDS broadcast,
//   W via coalesced vector loads (L2-resident 128 KB).
// All accumulation ascending-k fmaf -> bit-identical to round 2.
// ---------------------------------------------------------------------------
__global__ __launch_bounds__(640) void k_head(
    const float* __restrict__ img, const float* __restrict__ wt,
    const float* __restrict__ bd, float* __restrict__ depth_out,
    float* __restrict__ feat_ws) {
    __shared__ float smem[PXB * 132 + PXB];   // staging [64k x 66px] then X[66][132]
    float* S = smem + PXB * 132;

    const int tid = threadIdx.x;
    const int wv  = tid >> 6;            // 0..9
    const int ln  = tid & 63;
    const int p0  = blockIdx.x * PXB;    // tiles may cross (b,n): per-elem addressing
    const bool is_main = (wv < 8);
    const int o0  = __builtin_amdgcn_readfirstlane((is_main ? wv : 0) << 4);
    const int epx = 64 + (wv - 8);       // edge wave's pixel column (64 or 65)

    float acc[16];
#pragma unroll
    for (int j = 0; j < 16; ++j) acc[j] = 0.f;
    float acc2[2] = {0.f, 0.f};

    for (int kc = 0; kc < 4; ++kc) {
        // stage A chunk: 64 channels x 66 pixels (per-element addressed)
#pragma unroll
        for (int it = 0; it < 7; ++it) {
            int idx = tid + it * 640;
            if (idx < 64 * PXB) {
                int kl = idx / PXB, px = idx - kl * PXB;
                int p = p0 + px;
                int bn = p / HW, hw = p - bn * HW;
                smem[kl * PXB + px] =
                    img[((size_t)bn * CI + kc * 64 + kl) * HW + hw];
            }
        }
        __syncthreads();
        if (is_main) {
            const float* wr = wt + (size_t)(kc * 64) * 128 + o0;
#pragma unroll 4
            for (int k = 0; k < 64; ++k) {
                float a = smem[k * PXB + ln];
                const float* w = wr + k * 128;   // wave-uniform -> s_load
#pragma unroll
                for (int j = 0; j < 16; ++j)
                    acc[j] = fmaf(a, w[j], acc[j]);
            }
        } else {
#pragma unroll 4
            for (int k = 0; k < 64; ++k) {
                float a = smem[k * PXB + epx];   // uniform addr -> LDS broadcast
                const float* w = wt + (size_t)(kc * 64 + k) * 128;
                acc2[0] = fmaf(a, w[ln], acc2[0]);
                acc2[1] = fmaf(a, w[ln + 64], acc2[1]);  // wt zero-padded past 122
            }
        }
        __syncthreads();
    }

    // epilogue into X[66][132]: logits at col o (<59), feat at col o+5 (64..127)
    float* X = smem;
    if (is_main) {
#pragma unroll
        for (int j = 0; j < 16; ++j) {
            int o = o0 + j;
            if (o < NOUT) {
                int col = (o < D_BINS) ? o : o + 5;
                X[ln * 132 + col] = acc[j] + bd[o];
            }
        }
    } else {
        int o = ln;
        X[epx * 132 + ((o < D_BINS) ? o : o + 5)] = acc2[0] + bd[o];
        o = ln + 64;
        if (o < NOUT)
            X[epx * 132 + ((o < D_BINS) ? o : o + 5)] = acc2[1] + bd[o];
    }
    __syncthreads();

    // feat: X[p][64..127] -> feat_ws[(p0+p)*64 ...], coalesced float4
#pragma unroll
    for (int it = 0; it < 2; ++it) {
        int g = tid + it * 640;            // 66*16 = 1056 float4s
        if (g < PXB * 16) {
            int p = g >> 4, m = g & 15;
            float4 v = *(const float4*)(X + p * 132 + 64 + m * 4);
            *(float4*)(feat_ws + (size_t)(p0 + p) * CO + m * 4) = v;
        }
    }

    // softmax over cols 0..58, one thread per pixel
    if (tid < PXB) {
        float* row = X + tid * 132;
        float m = row[0];
        for (int o = 1; o < D_BINS; ++o) m = fmaxf(m, row[o]);
        float s = 0.f;
        for (int o = 0; o < D_BINS; ++o) {
            float e = __expf(row[o] - m);
            row[o] = e;
            s += e;
        }
        S[tid] = 1.f / s;
    }
    __syncthreads();

    // depth: block region contiguous [p0*59, (p0+66)*59) -> coalesced
    for (int g = tid; g < PXB * D_BINS; g += 640) {
        int p = g / D_BINS;
        int o = g - p * D_BINS;
        depth_out[(size_t)p0 * D_BINS + g] = X[p * 132 + o] * S[p];
    }
}

// ---------------------------------------------------------------------------
// Kernel 3: project voxels, gather depth weight + feat, splat to BEV.
// 512 blocks (2/CU, balanced). Thread owns one (b,y,x) cell x 32 channels
// (threadIdx.y = 2 y-cells x 2 channel-halves): projection VALU and depth
// gathers are 2x less redundant than the 16-ch layout. Per-sample float
// expressions identical to round 2 -> same valid/bin decisions bit-for-bit.
// ---------------------------------------------------------------------------
__global__ __launch_bounds__(256) void k_splat(
    const float* __restrict__ e2c, const float* __restrict__ Kmat,
    const float* __restrict__ depth_g, const float* __restrict__ feat_ws,
    float* __restrict__ bev) {
    const int tx   = threadIdx.x;           // 0..63 -> x
    const int half = threadIdx.y & 1;       // channel half (32 ch)
    const int yq   = threadIdx.y >> 1;      // 0..1 -> y sub-cell
    const int x = blockIdx.x * 64 + tx;
    const int y = blockIdx.y * 2 + yq;
    const int b = blockIdx.z;
    const float wx = (float)x * 0.8f + (-51.2f);
    const float wy = (float)y * 0.8f + (-51.2f);

    float acc[32];
#pragma unroll
    for (int m = 0; m < 32; ++m) acc[m] = 0.f;

    for (int n = 0; n < NC; ++n) {
        const int bn = b * NC + n;
        const float* E = e2c + bn * 12;
        const float* Km = Kmat + bn * 9;
        const float k00 = Km[0], k01 = Km[1], k02 = Km[2];
        const float k10 = Km[3], k11 = Km[4], k12 = Km[5];
        const float e02 = E[2], e12 = E[6], e22 = E[10];
        const float bx0 = E[0] * wx + E[1] * wy + E[3];
        const float bx1 = E[4] * wx + E[5] * wy + E[7];
        const float bx2 = E[8] * wx + E[9] * wy + E[11];
#pragma unroll
        for (int z = 0; z < ZD; ++z) {
            const float wz = -2.5f + (float)z;
            const float cx = bx0 + e02 * wz;
            const float cy = bx1 + e12 * wz;
            const float cz = bx2 + e22 * wz;
            const float zs = fmaxf(cz, 0.1f);
            const float rz = 1.0f / zs;         // IEEE divide
            const float xn = cx * rz;
            const float yn = cy * rz;
            const float fu = (k00 * xn + k01 * yn + k02) * 0.0625f;
            const float fv = (k10 * xn + k11 * yn + k12) * 0.0625f;
            const int bin = (int)(cz - 1.0f);   // trunc, matches astype(int32)
            const bool valid = (fu >= 0.f) & (fu < (float)W_IMG) &
                               (fv >= 0.f) & (fv < (float)H_IMG) &
                               (cz > 0.5f) & (bin >= 0) & (bin < D_BINS);
            if (valid) {
                int u = (int)fu;                // valid => already in range
                int v = (int)fv;
                int hw = v * W_IMG + u;
                float wgt = depth_g[((size_t)bn * HW + hw) * D_BINS + bin];
                const float4* fp =
                    (const float4*)(feat_ws + ((size_t)bn * HW + hw) * CO + half * 32);
#pragma unroll
                for (int q = 0; q < 8; ++q) {
                    float4 f = fp[q];
                    acc[q * 4 + 0] = fmaf(wgt, f.x, acc[q * 4 + 0]);
                    acc[q * 4 + 1] = fmaf(wgt, f.y, acc[q * 4 + 1]);
                    acc[q * 4 + 2] = fmaf(wgt, f.z, acc[q * 4 + 2]);
                    acc[q * 4 + 3] = fmaf(wgt, f.w, acc[q * 4 + 3]);
                }
            }
        }
    }
    // out[b][c][y][x], c = half*32 + m; 64 lanes = consecutive x -> coalesced
    float* ob = bev + (((size_t)b * CO + half * 32) * YD + y) * XD + x;
#pragma unroll
    for (int m = 0; m < 32; ++m) ob[(size_t)m * YD * XD] = acc[m];
}

extern "C" void kernel_launch(void* const* d_in, const int* in_sizes, int n_in,
                              void* d_out, int out_size, void* d_ws, size_t ws_size,
                              hipStream_t stream) {
    const float* img  = (const float*)d_in[0];  // (B,N,256,16,44)
    const float* c2e  = (const float*)d_in[1];  // (B,N,4,4)
    const float* Kmat = (const float*)d_in[2];  // (B,N,3,3)
    const float* wd   = (const float*)d_in[3];  // (123,256)
    const float* bd   = (const float*)d_in[4];  // (123,)
    float* bev = (float*)d_out;                         // (B,64,128,128)
    float* depth_out = bev + (size_t)NB * CO * YD * XD; // (B,N,16,44,59)
    float* feat_ws = (float*)d_ws;                      // NPIX*64 floats
    float* wt  = feat_ws + (size_t)NPIX * CO;           // 256*128 floats
    float* e2c = wt + 256 * 128;                        // 24*12 floats

    k_pre<<<128, 256, 0, stream>>>(wd, c2e, wt, e2c);
    k_head<<<256, 640, 0, stream>>>(img, wt, bd, depth_out, feat_ws);
    k_splat<<<dim3(2, 64, NB), dim3(64, 4, 1), 0, stream>>>(e2c, Kmat, depth_out,
                                                            feat_ws, bev);
}

// Round 4
// 126.332 us; speedup vs baseline: 1.0460x; 1.0460x over previous
//
#include <hip/hip_runtime.h>
#include <math.h>

#define D_BINS 59
#define CO     64
#define CI     256
#define NB     4
#define NC     6
#define H_IMG  16
#define W_IMG  44
#define HW     704            // H_IMG * W_IMG
#define NPIX   (NB*NC*HW)     // 16896
#define XD     128
#define YD     128
#define ZD     7
#define NOUT   123            // D_BINS + CO
#define PXB    66             // pixels per k_head block: 256 * 66 == NPIX exactly

typedef float v2f __attribute__((ext_vector_type(2)));

// ---------------------------------------------------------------------------
// Double-precision rigid-transform inverse (matches np.linalg.inv to ~1e-15,
// avoiding depth-bin boundary flips downstream).
// ---------------------------------------------------------------------------
__device__ void inv_rigid(const float* __restrict__ M, float* __restrict__ o) {
    double a = M[0], b = M[1], c = M[2], t0 = M[3];
    double d = M[4], e = M[5], f = M[6], t1 = M[7];
    double g = M[8], h = M[9], ii = M[10], t2 = M[11];
    double A00 = e*ii - f*h, A01 = c*h - b*ii, A02 = b*f - c*e;
    double A10 = f*g - d*ii, A11 = a*ii - c*g, A12 = c*d - a*f;
    double A20 = d*h - e*g,  A21 = b*g - a*h,  A22 = a*e - b*d;
    double det = a*A00 + b*A10 + c*A20;
    double inv = 1.0 / det;
    double r00 = A00*inv, r01 = A01*inv, r02 = A02*inv;
    double r10 = A10*inv, r11 = A11*inv, r12 = A12*inv;
    double r20 = A20*inv, r21 = A21*inv, r22 = A22*inv;
    o[0] = (float)r00; o[1] = (float)r01; o[2]  = (float)r02;
    o[3] = (float)(-(r00*t0 + r01*t1 + r02*t2));
    o[4] = (float)r10; o[5] = (float)r11; o[6]  = (float)r12;
    o[7] = (float)(-(r10*t0 + r11*t1 + r12*t2));
    o[8] = (float)r20; o[9] = (float)r21; o[10] = (float)r22;
    o[11] = (float)(-(r20*t0 + r21*t1 + r22*t2));
}

// ---------------------------------------------------------------------------
// Kernel 1: prep. W (123x256) -> wt2, k-pair-interleaved + transposed:
//   wt2[(k/2)*256 + o*2 + (k&1)],  o zero-padded to 128.
// Each o's {w_even, w_odd} pair is contiguous -> k_head gets float2 rows via
// the scalar cache and feeds v_pk_fma_f32. Block 0 also inverts cam2ego.
// ---------------------------------------------------------------------------
__global__ __launch_bounds__(256) void k_pre(
    const float* __restrict__ wd, const float* __restrict__ c2e,
    float* __restrict__ wt2, float* __restrict__ e2c) {
    const int o = blockIdx.x;   // 0..127
    const int k = threadIdx.x;  // 0..255
    float v = (o < NOUT) ? wd[(size_t)o * CI + k] : 0.f;
    wt2[(size_t)(k >> 1) * 256 + o * 2 + (k & 1)] = v;
    if (blockIdx.x == 0 && k < NB * NC)
        inv_rigid(c2e + k * 16, e2c + k * 12);
}

// ---------------------------------------------------------------------------
// Kernel 2: depth/feat head. 256 blocks x 66 px (perfect CU balance).
// Waves 0..7: lane = px, wave-uniform o-strip of 16. Per k-PAIR:
//   1 conflict-free ds_read_b64 (A, k-interleaved LDS) +
//   16 v_pk_fma_f32 (dual k-parity partial sums, W pairs from s_load).
// VALU issue halves vs scalar fmaf (8 insts/k); LDS b32 count halves via b64.
// Waves 8..9: leftover px columns 64/65 (LDS broadcast A, vector W loads).
// Even/odd partial sums merged at the end (fp reorder only; threshold 33x).
// ---------------------------------------------------------------------------
__global__ __launch_bounds__(640) void k_head(
    const float* __restrict__ img, const float* __restrict__ wt2,
    const float* __restrict__ bd, float* __restrict__ depth_out,
    float* __restrict__ feat_ws) {
    __shared__ float smem[PXB * 132 + PXB];  // A: 32 kp x 132 during GEMM; X after
    float* S = smem + PXB * 132;

    const int tid = threadIdx.x;
    const int wv  = tid >> 6;            // 0..9
    const int ln  = tid & 63;
    const int p0  = blockIdx.x * PXB;    // tiles may cross (b,n): per-elem addressing
    const bool is_main = (wv < 8);
    const int o0  = __builtin_amdgcn_readfirstlane((is_main ? wv : 0) << 4);
    const int epx = 64 + (wv - 8);       // edge wave's pixel column (64 or 65)

    v2f acc[16];                          // [o-within-strip] = {even-k, odd-k}
#pragma unroll
    for (int j = 0; j < 16; ++j) acc[j] = (v2f)(0.f);
    v2f acc2a = (v2f)(0.f), acc2b = (v2f)(0.f);

    for (int kc = 0; kc < 4; ++kc) {
        // stage A chunk k-interleaved: smem[(kl/2)*132 + px*2 + (kl&1)]
#pragma unroll
        for (int it = 0; it < 7; ++it) {
            int idx = tid + it * 640;
            if (idx < 64 * PXB) {
                int kl = idx / PXB, px = idx - kl * PXB;
                int p = p0 + px;
                int bn = p / HW, hw = p - bn * HW;
                smem[(kl >> 1) * 132 + px * 2 + (kl & 1)] =
                    img[((size_t)bn * CI + kc * 64 + kl) * HW + hw];
            }
        }
        __syncthreads();
        if (is_main) {
#pragma unroll 4
            for (int k2 = 0; k2 < 32; ++k2) {
                v2f a = *(const v2f*)(smem + k2 * 132 + ln * 2);  // stride-8B: free
                const v2f* w =
                    (const v2f*)(wt2 + (size_t)(kc * 32 + k2) * 256) + o0; // uniform
#pragma unroll
                for (int j = 0; j < 16; ++j)
                    acc[j] = __builtin_elementwise_fma(a, w[j], acc[j]);
            }
        } else {
#pragma unroll 4
            for (int k2 = 0; k2 < 32; ++k2) {
                v2f a = *(const v2f*)(smem + k2 * 132 + epx * 2);  // broadcast
                const float* w = wt2 + (size_t)(kc * 32 + k2) * 256;
                v2f w0 = {w[ln * 2], w[ln * 2 + 1]};
                v2f w1 = {w[(ln + 64) * 2], w[(ln + 64) * 2 + 1]};
                acc2a = __builtin_elementwise_fma(a, w0, acc2a);
                acc2b = __builtin_elementwise_fma(a, w1, acc2b);
            }
        }
        __syncthreads();
    }

    // epilogue into X[66][132]: logits at col o (<59), feat at col o+5 (64..127)
    float* X = smem;
    if (is_main) {
#pragma unroll
        for (int j = 0; j < 16; ++j) {
            int o = o0 + j;
            if (o < NOUT) {
                int col = (o < D_BINS) ? o : o + 5;
                X[ln * 132 + col] = (acc[j].x + acc[j].y) + bd[o];
            }
        }
    } else {
        int o = ln;
        X[epx * 132 + ((o < D_BINS) ? o : o + 5)] = (acc2a.x + acc2a.y) + bd[o];
        o = ln + 64;
        if (o < NOUT)
            X[epx * 132 + ((o < D_BINS) ? o : o + 5)] = (acc2b.x + acc2b.y) + bd[o];
    }
    __syncthreads();

    // feat: X[p][64..127] -> feat_ws[(p0+p)*64 ...], coalesced float4
#pragma unroll
    for (int it = 0; it < 2; ++it) {
        int g = tid + it * 640;            // 66*16 = 1056 float4s
        if (g < PXB * 16) {
            int p = g >> 4, m = g & 15;
            float4 v = *(const float4*)(X + p * 132 + 64 + m * 4);
            *(float4*)(feat_ws + (size_t)(p0 + p) * CO + m * 4) = v;
        }
    }

    // softmax over cols 0..58, one thread per pixel
    if (tid < PXB) {
        float* row = X + tid * 132;
        float m = row[0];
        for (int o = 1; o < D_BINS; ++o) m = fmaxf(m, row[o]);
        float s = 0.f;
        for (int o = 0; o < D_BINS; ++o) {
            float e = __expf(row[o] - m);
            row[o] = e;
            s += e;
        }
        S[tid] = 1.f / s;
    }
    __syncthreads();

    // depth: block region contiguous [p0*59, (p0+66)*59) -> coalesced
    for (int g = tid; g < PXB * D_BINS; g += 640) {
        int p = g / D_BINS;
        int o = g - p * D_BINS;
        depth_out[(size_t)p0 * D_BINS + g] = X[p * 132 + o] * S[p];
    }
}

// ---------------------------------------------------------------------------
// Kernel 3: project voxels, gather depth weight + feat, splat to BEV.
// Round-2 shape (best measured): 1024 blocks (4/CU, 16 waves/CU for gather
// latency hiding). Thread owns one (b,y,x) cell x 16 channels; per channel,
// 64 lanes write 64 consecutive x -> coalesced stores.
// ---------------------------------------------------------------------------
__global__ __launch_bounds__(256) void k_splat(
    const float* __restrict__ e2c, const float* __restrict__ Kmat,
    const float* __restrict__ depth_g, const float* __restrict__ feat_ws,
    float* __restrict__ bev) {
    const int tx = threadIdx.x;          // 0..63 -> x
    const int cq = threadIdx.y;          // 0..3  -> channel quarter
    const int x = blockIdx.x * 64 + tx;
    const int y = blockIdx.y;
    const int b = blockIdx.z;
    const float wx = (float)x * 0.8f + (-51.2f);
    const float wy = (float)y * 0.8f + (-51.2f);

    float acc[16];
#pragma unroll
    for (int m = 0; m < 16; ++m) acc[m] = 0.f;

    for (int n = 0; n < NC; ++n) {
        const int bn = b * NC + n;
        const float* E = e2c + bn * 12;
        const float* Km = Kmat + bn * 9;
        const float k00 = Km[0], k01 = Km[1], k02 = Km[2];
        const float k10 = Km[3], k11 = Km[4], k12 = Km[5];
        const float e02 = E[2], e12 = E[6], e22 = E[10];
        const float bx0 = E[0] * wx + E[1] * wy + E[3];
        const float bx1 = E[4] * wx + E[5] * wy + E[7];
        const float bx2 = E[8] * wx + E[9] * wy + E[11];
#pragma unroll
        for (int z = 0; z < ZD; ++z) {
            const float wz = -2.5f + (float)z;
            const float cx = bx0 + e02 * wz;
            const float cy = bx1 + e12 * wz;
            const float cz = bx2 + e22 * wz;
            const float zs = fmaxf(cz, 0.1f);
            const float rz = 1.0f / zs;         // IEEE divide
            const float xn = cx * rz;
            const float yn = cy * rz;
            const float fu = (k00 * xn + k01 * yn + k02) * 0.0625f;
            const float fv = (k10 * xn + k11 * yn + k12) * 0.0625f;
            const int bin = (int)(cz - 1.0f);   // trunc, matches astype(int32)
            const bool valid = (fu >= 0.f) & (fu < (float)W_IMG) &
                               (fv >= 0.f) & (fv < (float)H_IMG) &
                               (cz > 0.5f) & (bin >= 0) & (bin < D_BINS);
            if (valid) {
                int u = (int)fu;                // valid => already in range
                int v = (int)fv;
                int hw = v * W_IMG + u;
                float wgt = depth_g[((size_t)bn * HW + hw) * D_BINS + bin];
                const float4* fp =
                    (const float4*)(feat_ws + ((size_t)bn * HW + hw) * CO + cq * 16);
                float4 f0 = fp[0], f1 = fp[1], f2 = fp[2], f3 = fp[3];
                acc[0]  = fmaf(wgt, f0.x, acc[0]);
                acc[1]  = fmaf(wgt, f0.y, acc[1]);
                acc[2]  = fmaf(wgt, f0.z, acc[2]);
                acc[3]  = fmaf(wgt, f0.w, acc[3]);
                acc[4]  = fmaf(wgt, f1.x, acc[4]);
                acc[5]  = fmaf(wgt, f1.y, acc[5]);
                acc[6]  = fmaf(wgt, f1.z, acc[6]);
                acc[7]  = fmaf(wgt, f1.w, acc[7]);
                acc[8]  = fmaf(wgt, f2.x, acc[8]);
                acc[9]  = fmaf(wgt, f2.y, acc[9]);
                acc[10] = fmaf(wgt, f2.z, acc[10]);
                acc[11] = fmaf(wgt, f2.w, acc[11]);
                acc[12] = fmaf(wgt, f3.x, acc[12]);
                acc[13] = fmaf(wgt, f3.y, acc[13]);
                acc[14] = fmaf(wgt, f3.z, acc[14]);
                acc[15] = fmaf(wgt, f3.w, acc[15]);
            }
        }
    }
    // out[b][c][y][x], c = cq*16 + m
    float* ob = bev + (((size_t)b * CO + cq * 16) * YD + y) * XD + x;
#pragma unroll
    for (int m = 0; m < 16; ++m) ob[(size_t)m * YD * XD] = acc[m];
}

extern "C" void kernel_launch(void* const* d_in, const int* in_sizes, int n_in,
                              void* d_out, int out_size, void* d_ws, size_t ws_size,
                              hipStream_t stream) {
    const float* img  = (const float*)d_in[0];  // (B,N,256,16,44)
    const float* c2e  = (const float*)d_in[1];  // (B,N,4,4)
    const float* Kmat = (const float*)d_in[2];  // (B,N,3,3)
    const float* wd   = (const float*)d_in[3];  // (123,256)
    const float* bd   = (const float*)d_in[4];  // (123,)
    float* bev = (float*)d_out;                         // (B,64,128,128)
    float* depth_out = bev + (size_t)NB * CO * YD * XD; // (B,N,16,44,59)
    float* feat_ws = (float*)d_ws;                      // NPIX*64 floats
    float* wt2 = feat_ws + (size_t)NPIX * CO;           // 128*256 floats
    float* e2c = wt2 + 128 * 256;                       // 24*12 floats

    k_pre<<<128, 256, 0, stream>>>(wd, c2e, wt2, e2c);
    k_head<<<256, 640, 0, stream>>>(img, wt2, bd, depth_out, feat_ws);
    k_splat<<<dim3(2, YD, NB), dim3(64, 4, 1), 0, stream>>>(e2c, Kmat, depth_out,
                                                            feat_ws, bev);
}

// Round 5
// 124.250 us; speedup vs baseline: 1.0635x; 1.0168x over previous
//
#include <hip/hip_runtime.h>
#include <math.h>

#define D_BINS 59
#define CO     64
#define CI     256
#define NB     4
#define NC     6
#define H_IMG  16
#define W_IMG  44
#define HW     704            // H_IMG * W_IMG
#define NPIX   (NB*NC*HW)     // 16896
#define XD     128
#define YD     128
#define ZD     7
#define NOUT   123            // D_BINS + CO
#define PXB    66             // pixels per k_head block: 256 * 66 == NPIX exactly

typedef float v2f __attribute__((ext_vector_type(2)));

// ---------------------------------------------------------------------------
// Double-precision rigid-transform inverse (matches np.linalg.inv to ~1e-15,
// avoiding depth-bin boundary flips downstream).
// ---------------------------------------------------------------------------
__device__ void inv_rigid(const float* __restrict__ M, float* __restrict__ o) {
    double a = M[0], b = M[1], c = M[2], t0 = M[3];
    double d = M[4], e = M[5], f = M[6], t1 = M[7];
    double g = M[8], h = M[9], ii = M[10], t2 = M[11];
    double A00 = e*ii - f*h, A01 = c*h - b*ii, A02 = b*f - c*e;
    double A10 = f*g - d*ii, A11 = a*ii - c*g, A12 = c*d - a*f;
    double A20 = d*h - e*g,  A21 = b*g - a*h,  A22 = a*e - b*d;
    double det = a*A00 + b*A10 + c*A20;
    double inv = 1.0 / det;
    double r00 = A00*inv, r01 = A01*inv, r02 = A02*inv;
    double r10 = A10*inv, r11 = A11*inv, r12 = A12*inv;
    double r20 = A20*inv, r21 = A21*inv, r22 = A22*inv;
    o[0] = (float)r00; o[1] = (float)r01; o[2]  = (float)r02;
    o[3] = (float)(-(r00*t0 + r01*t1 + r02*t2));
    o[4] = (float)r10; o[5] = (float)r11; o[6]  = (float)r12;
    o[7] = (float)(-(r10*t0 + r11*t1 + r12*t2));
    o[8] = (float)r20; o[9] = (float)r21; o[10] = (float)r22;
    o[11] = (float)(-(r20*t0 + r21*t1 + r22*t2));
}

// ---------------------------------------------------------------------------
// Kernel 1: prep. W (123x256) -> wt2, k-pair-interleaved + transposed:
//   wt2[(k/2)*256 + o*2 + (k&1)],  o zero-padded to 128.
// Each o's {w_even, w_odd} pair is contiguous -> k_head gets float2 rows via
// the scalar cache and feeds v_pk_fma_f32. Block 0 also inverts cam2ego.
// ---------------------------------------------------------------------------
__global__ __launch_bounds__(256) void k_pre(
    const float* __restrict__ wd, const float* __restrict__ c2e,
    float* __restrict__ wt2, float* __restrict__ e2c) {
    const int o = blockIdx.x;   // 0..127
    const int k = threadIdx.x;  // 0..255
    float v = (o < NOUT) ? wd[(size_t)o * CI + k] : 0.f;
    wt2[(size_t)(k >> 1) * 256 + o * 2 + (k & 1)] = v;
    if (blockIdx.x == 0 && k < NB * NC)
        inv_rigid(c2e + k * 16, e2c + k * 12);
}

// ---------------------------------------------------------------------------
// Kernel 2: depth/feat head. 256 blocks x 66 px (perfect CU balance).
// Waves 0..7: lane = px, wave-uniform o-strip of 16. Per k-PAIR:
//   1 conflict-free ds_read_b64 (A, k-interleaved LDS) +
//   16 v_pk_fma_f32 (dual k-parity partial sums, W pairs from s_load).
// Waves 8..9: leftover px columns 64/65 (LDS broadcast A, coalesced W loads).
// Unchanged from round 4 (matched prediction).
// ---------------------------------------------------------------------------
__global__ __launch_bounds__(640) void k_head(
    const float* __restrict__ img, const float* __restrict__ wt2,
    const float* __restrict__ bd, float* __restrict__ depth_out,
    float* __restrict__ feat_ws) {
    __shared__ float smem[PXB * 132 + PXB];  // A: 32 kp x 132 during GEMM; X after
    float* S = smem + PXB * 132;

    const int tid = threadIdx.x;
    const int wv  = tid >> 6;            // 0..9
    const int ln  = tid & 63;
    const int p0  = blockIdx.x * PXB;    // tiles may cross (b,n): per-elem addressing
    const bool is_main = (wv < 8);
    const int o0  = __builtin_amdgcn_readfirstlane((is_main ? wv : 0) << 4);
    const int epx = 64 + (wv - 8);       // edge wave's pixel column (64 or 65)

    v2f acc[16];                          // [o-within-strip] = {even-k, odd-k}
#pragma unroll
    for (int j = 0; j < 16; ++j) acc[j] = (v2f)(0.f);
    v2f acc2a = (v2f)(0.f), acc2b = (v2f)(0.f);

    for (int kc = 0; kc < 4; ++kc) {
        // stage A chunk k-interleaved: smem[(kl/2)*132 + px*2 + (kl&1)]
#pragma unroll
        for (int it = 0; it < 7; ++it) {
            int idx = tid + it * 640;
            if (idx < 64 * PXB) {
                int kl = idx / PXB, px = idx - kl * PXB;
                int p = p0 + px;
                int bn = p / HW, hw = p - bn * HW;
                smem[(kl >> 1) * 132 + px * 2 + (kl & 1)] =
                    img[((size_t)bn * CI + kc * 64 + kl) * HW + hw];
            }
        }
        __syncthreads();
        if (is_main) {
#pragma unroll 4
            for (int k2 = 0; k2 < 32; ++k2) {
                v2f a = *(const v2f*)(smem + k2 * 132 + ln * 2);  // stride-8B: free
                const v2f* w =
                    (const v2f*)(wt2 + (size_t)(kc * 32 + k2) * 256) + o0; // uniform
#pragma unroll
                for (int j = 0; j < 16; ++j)
                    acc[j] = __builtin_elementwise_fma(a, w[j], acc[j]);
            }
        } else {
#pragma unroll 4
            for (int k2 = 0; k2 < 32; ++k2) {
                v2f a = *(const v2f*)(smem + k2 * 132 + epx * 2);  // broadcast
                const float* w = wt2 + (size_t)(kc * 32 + k2) * 256;
                v2f w0 = {w[ln * 2], w[ln * 2 + 1]};
                v2f w1 = {w[(ln + 64) * 2], w[(ln + 64) * 2 + 1]};
                acc2a = __builtin_elementwise_fma(a, w0, acc2a);
                acc2b = __builtin_elementwise_fma(a, w1, acc2b);
            }
        }
        __syncthreads();
    }

    // epilogue into X[66][132]: logits at col o (<59), feat at col o+5 (64..127)
    float* X = smem;
    if (is_main) {
#pragma unroll
        for (int j = 0; j < 16; ++j) {
            int o = o0 + j;
            if (o < NOUT) {
                int col = (o < D_BINS) ? o : o + 5;
                X[ln * 132 + col] = (acc[j].x + acc[j].y) + bd[o];
            }
        }
    } else {
        int o = ln;
        X[epx * 132 + ((o < D_BINS) ? o : o + 5)] = (acc2a.x + acc2a.y) + bd[o];
        o = ln + 64;
        if (o < NOUT)
            X[epx * 132 + ((o < D_BINS) ? o : o + 5)] = (acc2b.x + acc2b.y) + bd[o];
    }
    __syncthreads();

    // feat: X[p][64..127] -> feat_ws[(p0+p)*64 ...], coalesced float4
#pragma unroll
    for (int it = 0; it < 2; ++it) {
        int g = tid + it * 640;            // 66*16 = 1056 float4s
        if (g < PXB * 16) {
            int p = g >> 4, m = g & 15;
            float4 v = *(const float4*)(X + p * 132 + 64 + m * 4);
            *(float4*)(feat_ws + (size_t)(p0 + p) * CO + m * 4) = v;
        }
    }

    // softmax over cols 0..58, one thread per pixel
    if (tid < PXB) {
        float* row = X + tid * 132;
        float m = row[0];
        for (int o = 1; o < D_BINS; ++o) m = fmaxf(m, row[o]);
        float s = 0.f;
        for (int o = 0; o < D_BINS; ++o) {
            float e = __expf(row[o] - m);
            row[o] = e;
            s += e;
        }
        S[tid] = 1.f / s;
    }
    __syncthreads();

    // depth: block region contiguous [p0*59, (p0+66)*59) -> coalesced
    for (int g = tid; g < PXB * D_BINS; g += 640) {
        int p = g / D_BINS;
        int o = g - p * D_BINS;
        depth_out[(size_t)p0 * D_BINS + g] = X[p * 132 + o] * S[p];
    }
}

// ---------------------------------------------------------------------------
// Kernel 3: project voxels, gather depth weight + feat, splat to BEV.
// 1024 blocks (4/CU). NEW: per camera n, a projection phase computes each
// (x,z) sample's {hw, depth-weight} ONCE (was 4x redundant across the cq
// threads) into LDS; the accumulate phase broadcasts them to all 4 channel-
// quarter threads which do only their feat gathers + FMAs. Float expressions
// and n-outer/z-inner FMA order verbatim from round 4 -> bit-identical.
// ---------------------------------------------------------------------------
__global__ __launch_bounds__(256) void k_splat(
    const float* __restrict__ e2c, const float* __restrict__ Kmat,
    const float* __restrict__ depth_g, const float* __restrict__ feat_ws,
    float* __restrict__ bev) {
    __shared__ int   hw_s[ZD][64];
    __shared__ float wgt_s[ZD][64];

    const int tx = threadIdx.x;          // 0..63 -> x
    const int cq = threadIdx.y;          // 0..3  -> channel quarter / z-slice
    const int x = blockIdx.x * 64 + tx;
    const int y = blockIdx.y;
    const int b = blockIdx.z;
    const float wx = (float)x * 0.8f + (-51.2f);
    const float wy = (float)y * 0.8f + (-51.2f);

    float acc[16];
#pragma unroll
    for (int m = 0; m < 16; ++m) acc[m] = 0.f;

    for (int n = 0; n < NC; ++n) {
        const int bn = b * NC + n;
        const float* E = e2c + bn * 12;
        const float* Km = Kmat + bn * 9;
        const float k00 = Km[0], k01 = Km[1], k02 = Km[2];
        const float k10 = Km[3], k11 = Km[4], k12 = Km[5];
        const float e02 = E[2], e12 = E[6], e22 = E[10];
        const float bx0 = E[0] * wx + E[1] * wy + E[3];
        const float bx1 = E[4] * wx + E[5] * wy + E[7];
        const float bx2 = E[8] * wx + E[9] * wy + E[11];

        // ---- projection phase: thread (tx,cq) owns z = cq and cq+4 ----
#pragma unroll
        for (int zz = 0; zz < 2; ++zz) {
            const int z = cq + zz * 4;
            if (z < ZD) {
                const float wz = -2.5f + (float)z;
                const float cx = bx0 + e02 * wz;
                const float cy = bx1 + e12 * wz;
                const float cz = bx2 + e22 * wz;
                const float zs = fmaxf(cz, 0.1f);
                const float rz = 1.0f / zs;         // IEEE divide
                const float xn = cx * rz;
                const float yn = cy * rz;
                const float fu = (k00 * xn + k01 * yn + k02) * 0.0625f;
                const float fv = (k10 * xn + k11 * yn + k12) * 0.0625f;
                const int bin = (int)(cz - 1.0f);   // trunc, matches astype(int32)
                const bool valid = (fu >= 0.f) & (fu < (float)W_IMG) &
                                   (fv >= 0.f) & (fv < (float)H_IMG) &
                                   (cz > 0.5f) & (bin >= 0) & (bin < D_BINS);
                int hw = -1;
                float wgt = 0.f;
                if (valid) {
                    int u = (int)fu;                // valid => in range
                    int v = (int)fv;
                    hw = v * W_IMG + u;
                    wgt = depth_g[((size_t)bn * HW + hw) * D_BINS + bin];
                }
                hw_s[z][tx] = hw;
                wgt_s[z][tx] = wgt;
            }
        }
        __syncthreads();

        // ---- accumulate phase: z ascending (same FMA order as round 4) ----
#pragma unroll
        for (int z = 0; z < ZD; ++z) {
            const int hw = hw_s[z][tx];       // 4 cq threads same addr: broadcast
            if (hw >= 0) {
                const float wgt = wgt_s[z][tx];
                const float4* fp =
                    (const float4*)(feat_ws + ((size_t)bn * HW + hw) * CO + cq * 16);
                float4 f0 = fp[0], f1 = fp[1], f2 = fp[2], f3 = fp[3];
                acc[0]  = fmaf(wgt, f0.x, acc[0]);
                acc[1]  = fmaf(wgt, f0.y, acc[1]);
                acc[2]  = fmaf(wgt, f0.z, acc[2]);
                acc[3]  = fmaf(wgt, f0.w, acc[3]);
                acc[4]  = fmaf(wgt, f1.x, acc[4]);
                acc[5]  = fmaf(wgt, f1.y, acc[5]);
                acc[6]  = fmaf(wgt, f1.z, acc[6]);
                acc[7]  = fmaf(wgt, f1.w, acc[7]);
                acc[8]  = fmaf(wgt, f2.x, acc[8]);
                acc[9]  = fmaf(wgt, f2.y, acc[9]);
                acc[10] = fmaf(wgt, f2.z, acc[10]);
                acc[11] = fmaf(wgt, f2.w, acc[11]);
                acc[12] = fmaf(wgt, f3.x, acc[12]);
                acc[13] = fmaf(wgt, f3.y, acc[13]);
                acc[14] = fmaf(wgt, f3.z, acc[14]);
                acc[15] = fmaf(wgt, f3.w, acc[15]);
            }
        }
        __syncthreads();   // LDS reused next n
    }
    // out[b][c][y][x], c = cq*16 + m; 64 lanes = consecutive x -> coalesced
    float* ob = bev + (((size_t)b * CO + cq * 16) * YD + y) * XD + x;
#pragma unroll
    for (int m = 0; m < 16; ++m) ob[(size_t)m * YD * XD] = acc[m];
}

extern "C" void kernel_launch(void* const* d_in, const int* in_sizes, int n_in,
                              void* d_out, int out_size, void* d_ws, size_t ws_size,
                              hipStream_t stream) {
    const float* img  = (const float*)d_in[0];  // (B,N,256,16,44)
    const float* c2e  = (const float*)d_in[1];  // (B,N,4,4)
    const float* Kmat = (const float*)d_in[2];  // (B,N,3,3)
    const float* wd   = (const float*)d_in[3];  // (123,256)
    const float* bd   = (const float*)d_in[4];  // (123,)
    float* bev = (float*)d_out;                         // (B,64,128,128)
    float* depth_out = bev + (size_t)NB * CO * YD * XD; // (B,N,16,44,59)
    float* feat_ws = (float*)d_ws;                      // NPIX*64 floats
    float* wt2 = feat_ws + (size_t)NPIX * CO;           // 128*256 floats
    float* e2c = wt2 + 128 * 256;                       // 24*12 floats

    k_pre<<<128, 256, 0, stream>>>(wd, c2e, wt2, e2c);
    k_head<<<256, 640, 0, stream>>>(img, wt2, bd, depth_out, feat_ws);
    k_splat<<<dim3(2, YD, NB), dim3(64, 4, 1), 0, stream>>>(e2c, Kmat, depth_out,
                                                            feat_ws, bev);
}